// Round 1
// baseline (962.308 us; speedup 1.0000x reference)
//
#include <hip/hip_runtime.h>
#include <math.h>

#define NN 50000
#define NE 800000
#define HD 128
#define DOUT 32

// ---------------- CSR build ----------------
__global__ void hist_kernel(const int* __restrict__ dst, int* __restrict__ counts) {
    int e = blockIdx.x * blockDim.x + threadIdx.x;
    if (e < NE) atomicAdd(&counts[dst[e]], 1);
}

__global__ __launch_bounds__(1024) void scan_kernel(const int* __restrict__ counts,
                                                    int* __restrict__ offsets,
                                                    int* __restrict__ cursor) {
    __shared__ int sm[1024];
    const int T = 1024;
    int tid = threadIdx.x;
    int per = (NN + T - 1) / T;   // 49
    int start = tid * per;
    int end = min(start + per, NN);
    if (start > NN) start = NN;
    int sum = 0;
    for (int i = start; i < end; ++i) sum += counts[i];
    sm[tid] = sum;
    __syncthreads();
    for (int off = 1; off < T; off <<= 1) {
        int v = (tid >= off) ? sm[tid - off] : 0;
        __syncthreads();
        sm[tid] += v;
        __syncthreads();
    }
    int run = sm[tid] - sum;   // exclusive prefix
    for (int i = start; i < end; ++i) {
        offsets[i] = run;
        cursor[i]  = run;
        run += counts[i];
    }
    if (tid == T - 1) offsets[NN] = sm[T - 1];
}

__global__ void fill_kernel(const int* __restrict__ src, const int* __restrict__ dst,
                            int* __restrict__ cursor, int* __restrict__ perm_src) {
    int e = blockIdx.x * blockDim.x + threadIdx.x;
    if (e < NE) {
        int d = dst[e];
        int pos = atomicAdd(&cursor[d], 1);
        perm_src[pos] = src[e];
    }
}

// ---------------- weight transpose: [384][128] -> [128][384] ----------------
__global__ void transpose4_kernel(const float* a, const float* b, const float* c, const float* d,
                                  float* oa, float* ob, float* oc, float* od) {
    const float* in; float* out;
    switch (blockIdx.y) {
        case 0: in = a; out = oa; break;
        case 1: in = b; out = ob; break;
        case 2: in = c; out = oc; break;
        default: in = d; out = od; break;
    }
    int id = blockIdx.x * blockDim.x + threadIdx.x;
    if (id < 384 * HD) {
        int k = id / 384, j = id % 384;
        out[id] = in[j * HD + k];
    }
}

// ---------------- generic K=128 GEMM: C[N,P] = act(A[N,128] @ B[128,P] + bias) ----------------
// P = 32*JB. Block 256 thr: tx = t&31 (col lane), ty = t>>5 (8 row-groups of 8 rows). Tile 64 rows.
template<int JB, bool RELU>
__global__ __launch_bounds__(256) void gemm_k128_kernel(const float* __restrict__ A,
                                                        const float* __restrict__ B,
                                                        const float* __restrict__ bias,
                                                        float* __restrict__ C) {
    __shared__ float At[HD][68];   // transposed A tile [k][n], pad 68 (16B-aligned rows)
    const int P = 32 * JB;
    int n0 = blockIdx.x * 64;
    int tx = threadIdx.x & 31;
    int ty = threadIdx.x >> 5;

    #pragma unroll
    for (int it = 0; it < 8; ++it) {
        int idx = threadIdx.x + it * 256;   // 0..2047 float4 slots
        int n = idx >> 5;
        int kq = idx & 31;
        float4 v = make_float4(0.f, 0.f, 0.f, 0.f);
        if (n0 + n < NN) v = *reinterpret_cast<const float4*>(&A[(n0 + n) * HD + kq * 4]);
        At[kq * 4 + 0][n] = v.x;
        At[kq * 4 + 1][n] = v.y;
        At[kq * 4 + 2][n] = v.z;
        At[kq * 4 + 3][n] = v.w;
    }
    __syncthreads();

    float acc[JB][8];
    #pragma unroll
    for (int jb = 0; jb < JB; ++jb)
        #pragma unroll
        for (int i = 0; i < 8; ++i) acc[jb][i] = 0.f;

    #pragma unroll 4
    for (int k = 0; k < HD; ++k) {
        float4 a0 = *reinterpret_cast<const float4*>(&At[k][ty * 8]);
        float4 a1 = *reinterpret_cast<const float4*>(&At[k][ty * 8 + 4]);
        float av[8] = {a0.x, a0.y, a0.z, a0.w, a1.x, a1.y, a1.z, a1.w};
        #pragma unroll
        for (int jb = 0; jb < JB; ++jb) {
            float bv = B[k * P + jb * 32 + tx];
            #pragma unroll
            for (int i = 0; i < 8; ++i) acc[jb][i] += av[i] * bv;
        }
    }

    #pragma unroll
    for (int jb = 0; jb < JB; ++jb) {
        int j = jb * 32 + tx;
        float bs = bias ? bias[j] : 0.f;
        #pragma unroll
        for (int i = 0; i < 8; ++i) {
            int n = ty * 8 + i;
            if (n0 + n < NN) {
                float v = acc[jb][i] + bs;
                if (RELU) v = fmaxf(v, 0.f);
                C[(n0 + n) * P + j] = v;
            }
        }
    }
}

// ---------------- CSR aggregate: agg[n,:] = sum_{e in in-edges(n)} m[src_e,:] ----------------
__global__ __launch_bounds__(256) void aggregate_kernel(const float* __restrict__ m,
                                                        const int* __restrict__ offsets,
                                                        const int* __restrict__ perm_src,
                                                        float* __restrict__ agg) {
    int node = blockIdx.x * 8 + (threadIdx.x >> 5);
    if (node >= NN) return;
    int q = (threadIdx.x & 31) * 4;
    int beg = offsets[node], end = offsets[node + 1];
    float4 acc = make_float4(0.f, 0.f, 0.f, 0.f);
    int e = beg;
    for (; e + 2 <= end; e += 2) {
        int s0 = perm_src[e], s1 = perm_src[e + 1];
        float4 v0 = *reinterpret_cast<const float4*>(&m[s0 * HD + q]);
        float4 v1 = *reinterpret_cast<const float4*>(&m[s1 * HD + q]);
        acc.x += v0.x + v1.x; acc.y += v0.y + v1.y;
        acc.z += v0.z + v1.z; acc.w += v0.w + v1.w;
    }
    if (e < end) {
        float4 v = *reinterpret_cast<const float4*>(&m[perm_src[e] * HD + q]);
        acc.x += v.x; acc.y += v.y; acc.z += v.z; acc.w += v.w;
    }
    *reinterpret_cast<float4*>(&agg[node * HD + q]) = acc;
}

// ---------------- fused GRU update ----------------
// h' = (1-z)*n + z*h, r=sig(Wir a + Whr h + b), z=sig(...), n=tanh(Win a + b + r*(Whn h + b))
// wihT/whhT are [128][384] k-major. One block = 64-node tile.
__global__ __launch_bounds__(256) void gru_kernel(const float* __restrict__ agg,
                                                  const float* __restrict__ h,
                                                  const float* __restrict__ wihT,
                                                  const float* __restrict__ whhT,
                                                  const float* __restrict__ bih,
                                                  const float* __restrict__ bhh,
                                                  float* __restrict__ hout) {
    __shared__ float At[HD][68];
    __shared__ float Ht[HD][68];
    int n0 = blockIdx.x * 64;
    int tx = threadIdx.x & 31;
    int ty = threadIdx.x >> 5;

    #pragma unroll
    for (int it = 0; it < 8; ++it) {
        int idx = threadIdx.x + it * 256;
        int n = idx >> 5;
        int kq = idx & 31;
        float4 va = make_float4(0.f, 0.f, 0.f, 0.f);
        float4 vh = make_float4(0.f, 0.f, 0.f, 0.f);
        if (n0 + n < NN) {
            va = *reinterpret_cast<const float4*>(&agg[(n0 + n) * HD + kq * 4]);
            vh = *reinterpret_cast<const float4*>(&h[(n0 + n) * HD + kq * 4]);
        }
        At[kq * 4 + 0][n] = va.x; At[kq * 4 + 1][n] = va.y;
        At[kq * 4 + 2][n] = va.z; At[kq * 4 + 3][n] = va.w;
        Ht[kq * 4 + 0][n] = vh.x; Ht[kq * 4 + 1][n] = vh.y;
        Ht[kq * 4 + 2][n] = vh.z; Ht[kq * 4 + 3][n] = vh.w;
    }
    __syncthreads();

    for (int jj = 0; jj < 4; ++jj) {
        int j = jj * 32 + tx;   // output col 0..127
        float air[8], ahr[8], aiz[8], ahz[8], ain[8], ahn[8];
        #pragma unroll
        for (int i = 0; i < 8; ++i) { air[i]=0.f; ahr[i]=0.f; aiz[i]=0.f; ahz[i]=0.f; ain[i]=0.f; ahn[i]=0.f; }

        #pragma unroll 2
        for (int k = 0; k < HD; ++k) {
            float4 a0 = *reinterpret_cast<const float4*>(&At[k][ty * 8]);
            float4 a1 = *reinterpret_cast<const float4*>(&At[k][ty * 8 + 4]);
            float4 h0 = *reinterpret_cast<const float4*>(&Ht[k][ty * 8]);
            float4 h1 = *reinterpret_cast<const float4*>(&Ht[k][ty * 8 + 4]);
            float av[8] = {a0.x, a0.y, a0.z, a0.w, a1.x, a1.y, a1.z, a1.w};
            float hv[8] = {h0.x, h0.y, h0.z, h0.w, h1.x, h1.y, h1.z, h1.w};
            float wir = wihT[k * 384 + j];
            float wiz = wihT[k * 384 + 128 + j];
            float win = wihT[k * 384 + 256 + j];
            float whr = whhT[k * 384 + j];
            float whz = whhT[k * 384 + 128 + j];
            float whn = whhT[k * 384 + 256 + j];
            #pragma unroll
            for (int i = 0; i < 8; ++i) {
                air[i] += av[i] * wir;
                aiz[i] += av[i] * wiz;
                ain[i] += av[i] * win;
                ahr[i] += hv[i] * whr;
                ahz[i] += hv[i] * whz;
                ahn[i] += hv[i] * whn;
            }
        }

        float bir = bih[j], biz = bih[128 + j], bin = bih[256 + j];
        float bhr = bhh[j], bhz = bhh[128 + j], bhn = bhh[256 + j];
        #pragma unroll
        for (int i = 0; i < 8; ++i) {
            int n = ty * 8 + i;
            if (n0 + n < NN) {
                float r = 1.f / (1.f + __expf(-(air[i] + bir + ahr[i] + bhr)));
                float z = 1.f / (1.f + __expf(-(aiz[i] + biz + ahz[i] + bhz)));
                float pre = ain[i] + bin + r * (ahn[i] + bhn);
                float e2 = __expf(2.f * pre);
                float nn_ = (e2 - 1.f) / (e2 + 1.f);   // tanh
                float hv_ = Ht[j][n];                  // h[n][j]
                hout[(n0 + n) * HD + j] = (1.f - z) * nn_ + z * hv_;
            }
        }
    }
}

// ---------------- launch ----------------
extern "C" void kernel_launch(void* const* d_in, const int* in_sizes, int n_in,
                              void* d_out, int out_size, void* d_ws, size_t ws_size,
                              hipStream_t stream) {
    const float* x      = (const float*)d_in[0];
    const int*   eidx   = (const int*)d_in[1];
    const float* W_in   = (const float*)d_in[2];
    const float* b_in   = (const float*)d_in[3];
    const float* W_msg0 = (const float*)d_in[4];
    const float* wih0   = (const float*)d_in[5];
    const float* whh0   = (const float*)d_in[6];
    const float* bih0   = (const float*)d_in[7];
    const float* bhh0   = (const float*)d_in[8];
    const float* W_msg1 = (const float*)d_in[9];
    const float* wih1   = (const float*)d_in[10];
    const float* whh1   = (const float*)d_in[11];
    const float* bih1   = (const float*)d_in[12];
    const float* bhh1   = (const float*)d_in[13];
    const float* W_out  = (const float*)d_in[14];
    const float* b_out  = (const float*)d_in[15];
    float* out = (float*)d_out;

    const int* src = eidx;
    const int* dst = eidx + NE;

    char* ws = (char*)d_ws;
    size_t off = 0;
    auto alloc = [&](size_t bytes) {
        void* p = ws + off;
        off += (bytes + 255) & ~(size_t)255;
        return p;
    };
    float* buf0  = (float*)alloc((size_t)NN * HD * 4);
    float* buf1  = (float*)alloc((size_t)NN * HD * 4);
    float* buf2  = (float*)alloc((size_t)NN * HD * 4);
    float* wihT0 = (float*)alloc(384 * HD * 4);
    float* whhT0 = (float*)alloc(384 * HD * 4);
    float* wihT1 = (float*)alloc(384 * HD * 4);
    float* whhT1 = (float*)alloc(384 * HD * 4);
    int* counts  = (int*)alloc(NN * 4);
    int* offsets = (int*)alloc((NN + 1) * 4);
    int* cursor  = (int*)alloc(NN * 4);
    int* perm    = (int*)alloc(NE * 4);

    // CSR build
    hipMemsetAsync(counts, 0, NN * 4, stream);
    hist_kernel<<<(NE + 255) / 256, 256, 0, stream>>>(dst, counts);
    scan_kernel<<<1, 1024, 0, stream>>>(counts, offsets, cursor);
    fill_kernel<<<(NE + 255) / 256, 256, 0, stream>>>(src, dst, cursor, perm);

    // weight transposes
    dim3 tg((384 * HD + 255) / 256, 4);
    transpose4_kernel<<<tg, 256, 0, stream>>>(wih0, whh0, wih1, whh1, wihT0, whhT0, wihT1, whhT1);

    int ntiles = (NN + 63) / 64;   // 782

    // h0 = relu(x @ W_in + b_in)
    gemm_k128_kernel<4, true><<<ntiles, 256, 0, stream>>>(x, W_in, b_in, buf0);

    // layer 0
    gemm_k128_kernel<4, false><<<ntiles, 256, 0, stream>>>(buf0, W_msg0, nullptr, buf1);
    aggregate_kernel<<<(NN + 7) / 8, 256, 0, stream>>>(buf1, offsets, perm, buf2);
    gru_kernel<<<ntiles, 256, 0, stream>>>(buf2, buf0, wihT0, whhT0, bih0, bhh0, buf1);

    // layer 1
    gemm_k128_kernel<4, false><<<ntiles, 256, 0, stream>>>(buf1, W_msg1, nullptr, buf0);
    aggregate_kernel<<<(NN + 7) / 8, 256, 0, stream>>>(buf0, offsets, perm, buf2);
    gru_kernel<<<ntiles, 256, 0, stream>>>(buf2, buf1, wihT1, whhT1, bih1, bhh1, buf0);

    // out = h @ W_out + b_out
    gemm_k128_kernel<1, false><<<ntiles, 256, 0, stream>>>(buf0, W_out, b_out, out);
}

// Round 5
// 505.297 us; speedup vs baseline: 1.9044x; 1.9044x over previous
//
#include <hip/hip_runtime.h>
#include <hip/hip_bf16.h>
#include <math.h>

#define NN 50000
#define NE 800000
#define HD 128

typedef __attribute__((ext_vector_type(8))) short bf16x8;
typedef __attribute__((ext_vector_type(4))) float f32x4;

__device__ inline float b2f(unsigned short s) {
    union { unsigned int u; float f; } w; w.u = ((unsigned int)s) << 16; return w.f;
}
__device__ inline short f2b(float f) {
    __hip_bfloat16 h = __float2bfloat16(f);
    short s; __builtin_memcpy(&s, &h, 2); return s;
}

// ---------------- CSR build ----------------
__global__ void hist_kernel(const int* __restrict__ dst, int* __restrict__ counts) {
    int e = blockIdx.x * blockDim.x + threadIdx.x;
    if (e < NE) atomicAdd(&counts[dst[e]], 1);
}

__global__ __launch_bounds__(1024) void scan_kernel(const int* __restrict__ counts,
                                                    int* __restrict__ offsets,
                                                    int* __restrict__ cursor) {
    __shared__ int sm[1024];
    const int T = 1024;
    int tid = threadIdx.x;
    int per = (NN + T - 1) / T;
    int start = tid * per;
    int end = min(start + per, NN);
    if (start > NN) start = NN;
    int sum = 0;
    for (int i = start; i < end; ++i) sum += counts[i];
    sm[tid] = sum;
    __syncthreads();
    for (int off = 1; off < T; off <<= 1) {
        int v = (tid >= off) ? sm[tid - off] : 0;
        __syncthreads();
        sm[tid] += v;
        __syncthreads();
    }
    int run = sm[tid] - sum;
    for (int i = start; i < end; ++i) {
        offsets[i] = run;
        cursor[i]  = run;
        run += counts[i];
    }
    if (tid == T - 1) offsets[NN] = sm[T - 1];
}

__global__ void fill_kernel(const int* __restrict__ src, const int* __restrict__ dst,
                            int* __restrict__ cursor, int* __restrict__ perm_src) {
    int e = blockIdx.x * blockDim.x + threadIdx.x;
    if (e < NE) {
        int d = dst[e];
        int pos = atomicAdd(&cursor[d], 1);
        perm_src[pos] = src[e];
    }
}

// ---------------- weight pack: into per-lane MFMA B-fragment layout ----------------
// Bp[jt][ks][l][i] = B[k][j],  j = jt*16 + (l&15),  k = ks*32 + (l>>4)*8 + i
// kmajor source: B[k][j] = src[k*J + j]   (W_in / W_msg / W_out style)
// jmajor source: B[k][j] = src[j*128 + k] (wih / whh style, [J][128] row-major)
__global__ void pack_all(const float* W_in, const float* W_msg0, const float* W_msg1,
                         const float* W_out, const float* wih0, const float* whh0,
                         const float* wih1, const float* whh1,
                         short* pWin, short* pWm0, short* pWm1, short* pWout,
                         short* pI0, short* pH0, short* pI1, short* pH1) {
    const float* src; short* dst; int JT; bool kmajor; int J;
    switch (blockIdx.y) {
        case 0: src = W_in;   dst = pWin;  JT = 8;  kmajor = true;  J = 128; break;
        case 1: src = W_msg0; dst = pWm0;  JT = 8;  kmajor = true;  J = 128; break;
        case 2: src = W_msg1; dst = pWm1;  JT = 8;  kmajor = true;  J = 128; break;
        case 3: src = W_out;  dst = pWout; JT = 2;  kmajor = true;  J = 32;  break;
        case 4: src = wih0;   dst = pI0;   JT = 24; kmajor = false; J = 384; break;
        case 5: src = whh0;   dst = pH0;   JT = 24; kmajor = false; J = 384; break;
        case 6: src = wih1;   dst = pI1;   JT = 24; kmajor = false; J = 384; break;
        default: src = whh1;  dst = pH1;   JT = 24; kmajor = false; J = 384; break;
    }
    int t = blockIdx.x * 256 + threadIdx.x;
    if (t >= JT * 4 * 64) return;
    int l = t & 63, ks = (t >> 6) & 3, jt = t >> 8;
    int j = jt * 16 + (l & 15);
    int k0 = ks * 32 + (l >> 4) * 8;
    bf16x8 tv;
    if (kmajor) {
        #pragma unroll
        for (int i = 0; i < 8; ++i) tv[i] = f2b(src[(k0 + i) * J + j]);
    } else {
        #pragma unroll
        for (int i = 0; i < 8; ++i) tv[i] = f2b(src[j * 128 + k0 + i]);
    }
    *reinterpret_cast<bf16x8*>(dst + t * 8) = tv;
}

// ---------------- skinny MFMA GEMM: C[M,16*JT] = act(A[M,128] @ B + bias) ----------------
// Block: 4 waves x 32 rows = 128 rows. Per wave: 2 M-tiles of 16.
template<int JT, bool RELU, bool AF32, bool OUTF32>
__global__ __launch_bounds__(256) void gemm_mfma(const void* __restrict__ Av,
                                                 const short* __restrict__ Bp,
                                                 const float* __restrict__ bias,
                                                 void* __restrict__ Cv) {
    int w = threadIdx.x >> 6;
    int l = threadIdx.x & 63;
    int r0 = blockIdx.x * 128 + w * 32;
    int lr = l & 15;
    int lk = (l >> 4) * 8;

    bf16x8 a[2][4];
    #pragma unroll
    for (int mt = 0; mt < 2; ++mt) {
        int row = r0 + mt * 16 + lr;
        if (row > NN - 1) row = NN - 1;
        #pragma unroll
        for (int ks = 0; ks < 4; ++ks) {
            if (AF32) {
                const float* ap = (const float*)Av + (size_t)row * HD + ks * 32 + lk;
                float4 v0 = *(const float4*)ap;
                float4 v1 = *(const float4*)(ap + 4);
                bf16x8 tv;
                tv[0] = f2b(v0.x); tv[1] = f2b(v0.y); tv[2] = f2b(v0.z); tv[3] = f2b(v0.w);
                tv[4] = f2b(v1.x); tv[5] = f2b(v1.y); tv[6] = f2b(v1.z); tv[7] = f2b(v1.w);
                a[mt][ks] = tv;
            } else {
                a[mt][ks] = *reinterpret_cast<const bf16x8*>((const short*)Av + (size_t)row * HD + ks * 32 + lk);
            }
        }
    }

    #pragma unroll
    for (int jt = 0; jt < JT; ++jt) {
        f32x4 acc0 = {0.f, 0.f, 0.f, 0.f}, acc1 = {0.f, 0.f, 0.f, 0.f};
        const short* bp = Bp + ((jt * 4) * 64 + l) * 8;
        #pragma unroll
        for (int ks = 0; ks < 4; ++ks) {
            bf16x8 b = *reinterpret_cast<const bf16x8*>(bp + ks * 64 * 8);
            acc0 = __builtin_amdgcn_mfma_f32_16x16x32_bf16(a[0][ks], b, acc0, 0, 0, 0);
            acc1 = __builtin_amdgcn_mfma_f32_16x16x32_bf16(a[1][ks], b, acc1, 0, 0, 0);
        }
        int col = jt * 16 + lr;
        float bs = bias ? bias[col] : 0.f;
        #pragma unroll
        for (int mt = 0; mt < 2; ++mt) {
            f32x4 acc = mt ? acc1 : acc0;
            #pragma unroll
            for (int rg = 0; rg < 4; ++rg) {
                int row = r0 + mt * 16 + (l >> 4) * 4 + rg;
                if (row < NN) {
                    float v = acc[rg] + bs;
                    if (RELU) v = fmaxf(v, 0.f);
                    if (OUTF32) ((float*)Cv)[(size_t)row * (16 * JT) + col] = v;
                    else        ((short*)Cv)[(size_t)row * (16 * JT) + col] = f2b(v);
                }
            }
        }
    }
}

// ---------------- CSR aggregate (bf16 in, fp32 accum, bf16 out) ----------------
__global__ __launch_bounds__(256) void aggregate_bf16(const short* __restrict__ m,
                                                      const int* __restrict__ offsets,
                                                      const int* __restrict__ perm_src,
                                                      short* __restrict__ agg) {
    int node = blockIdx.x * 8 + (threadIdx.x >> 5);
    if (node >= NN) return;
    int q = (threadIdx.x & 31) * 4;
    int beg = offsets[node], end = offsets[node + 1];
    float a0 = 0.f, a1 = 0.f, a2 = 0.f, a3 = 0.f;
    int e = beg;
    for (; e + 2 <= end; e += 2) {
        int s0 = perm_src[e], s1 = perm_src[e + 1];
        ushort4 u0 = *reinterpret_cast<const ushort4*>(m + (size_t)s0 * HD + q);
        ushort4 u1 = *reinterpret_cast<const ushort4*>(m + (size_t)s1 * HD + q);
        a0 += b2f(u0.x) + b2f(u1.x);
        a1 += b2f(u0.y) + b2f(u1.y);
        a2 += b2f(u0.z) + b2f(u1.z);
        a3 += b2f(u0.w) + b2f(u1.w);
    }
    if (e < end) {
        ushort4 u = *reinterpret_cast<const ushort4*>(m + (size_t)perm_src[e] * HD + q);
        a0 += b2f(u.x); a1 += b2f(u.y); a2 += b2f(u.z); a3 += b2f(u.w);
    }
    ushort4 o;
    o.x = (unsigned short)f2b(a0); o.y = (unsigned short)f2b(a1);
    o.z = (unsigned short)f2b(a2); o.w = (unsigned short)f2b(a3);
    *reinterpret_cast<ushort4*>(agg + (size_t)node * HD + q) = o;
}

// ---------------- fused GRU via MFMA ----------------
// gi = agg @ wih^T, gh = h @ whh^T (both [rows,384] via packed frags), then gates.
__global__ __launch_bounds__(256) void gru_mfma(const short* __restrict__ agg,
                                                const short* __restrict__ h,
                                                const short* __restrict__ BpI,
                                                const short* __restrict__ BpH,
                                                const float* __restrict__ bih,
                                                const float* __restrict__ bhh,
                                                short* __restrict__ hout) {
    int w = threadIdx.x >> 6;
    int l = threadIdx.x & 63;
    int r0 = blockIdx.x * 128 + w * 32;
    int lr = l & 15;
    int lk = (l >> 4) * 8;

    bf16x8 aa[2][4], ah[2][4];
    #pragma unroll
    for (int mt = 0; mt < 2; ++mt) {
        int row = r0 + mt * 16 + lr;
        if (row > NN - 1) row = NN - 1;
        #pragma unroll
        for (int ks = 0; ks < 4; ++ks) {
            aa[mt][ks] = *reinterpret_cast<const bf16x8*>(agg + (size_t)row * HD + ks * 32 + lk);
            ah[mt][ks] = *reinterpret_cast<const bf16x8*>(h   + (size_t)row * HD + ks * 32 + lk);
        }
    }

    const f32x4 zero = {0.f, 0.f, 0.f, 0.f};
    #pragma unroll 1
    for (int jt = 0; jt < 8; ++jt) {
        f32x4 ir[2] = {zero, zero}, iz[2] = {zero, zero}, in_[2] = {zero, zero};
        f32x4 hr[2] = {zero, zero}, hz[2] = {zero, zero}, hn[2] = {zero, zero};
        #pragma unroll
        for (int ks = 0; ks < 4; ++ks) {
            const short* bi = BpI + ((jt * 4 + ks) * 64 + l) * 8;
            const short* bh = BpH + ((jt * 4 + ks) * 64 + l) * 8;
            bf16x8 bir = *reinterpret_cast<const bf16x8*>(bi);
            bf16x8 biz = *reinterpret_cast<const bf16x8*>(bi + 8 * 4 * 64 * 8);
            bf16x8 bin = *reinterpret_cast<const bf16x8*>(bi + 16 * 4 * 64 * 8);
            bf16x8 bhr = *reinterpret_cast<const bf16x8*>(bh);
            bf16x8 bhz = *reinterpret_cast<const bf16x8*>(bh + 8 * 4 * 64 * 8);
            bf16x8 bhn = *reinterpret_cast<const bf16x8*>(bh + 16 * 4 * 64 * 8);
            #pragma unroll
            for (int mt = 0; mt < 2; ++mt) {
                ir[mt]  = __builtin_amdgcn_mfma_f32_16x16x32_bf16(aa[mt][ks], bir, ir[mt],  0, 0, 0);
                iz[mt]  = __builtin_amdgcn_mfma_f32_16x16x32_bf16(aa[mt][ks], biz, iz[mt],  0, 0, 0);
                in_[mt] = __builtin_amdgcn_mfma_f32_16x16x32_bf16(aa[mt][ks], bin, in_[mt], 0, 0, 0);
                hr[mt]  = __builtin_amdgcn_mfma_f32_16x16x32_bf16(ah[mt][ks], bhr, hr[mt],  0, 0, 0);
                hz[mt]  = __builtin_amdgcn_mfma_f32_16x16x32_bf16(ah[mt][ks], bhz, hz[mt],  0, 0, 0);
                hn[mt]  = __builtin_amdgcn_mfma_f32_16x16x32_bf16(ah[mt][ks], bhn, hn[mt],  0, 0, 0);
            }
        }
        int col = jt * 16 + lr;
        float bir_ = bih[col], biz_ = bih[128 + col], bin_ = bih[256 + col];
        float bhr_ = bhh[col], bhz_ = bhh[128 + col], bhn_ = bhh[256 + col];
        #pragma unroll
        for (int mt = 0; mt < 2; ++mt) {
            #pragma unroll
            for (int rg = 0; rg < 4; ++rg) {
                int row = r0 + mt * 16 + (l >> 4) * 4 + rg;
                if (row < NN) {
                    float rr = 1.f / (1.f + __expf(-(ir[mt][rg] + bir_ + hr[mt][rg] + bhr_)));
                    float zz = 1.f / (1.f + __expf(-(iz[mt][rg] + biz_ + hz[mt][rg] + bhz_)));
                    float pre = in_[mt][rg] + bin_ + rr * (hn[mt][rg] + bhn_);
                    pre = fminf(fmaxf(pre, -20.f), 20.f);
                    float e2 = __expf(2.f * pre);
                    float nn_ = (e2 - 1.f) / (e2 + 1.f);
                    float hv = b2f((unsigned short)h[(size_t)row * HD + col]);
                    hout[(size_t)row * HD + col] = f2b((1.f - zz) * nn_ + zz * hv);
                }
            }
        }
    }
}

// ---------------- launch ----------------
extern "C" void kernel_launch(void* const* d_in, const int* in_sizes, int n_in,
                              void* d_out, int out_size, void* d_ws, size_t ws_size,
                              hipStream_t stream) {
    const float* x      = (const float*)d_in[0];
    const int*   eidx   = (const int*)d_in[1];
    const float* W_in   = (const float*)d_in[2];
    const float* b_in   = (const float*)d_in[3];
    const float* W_msg0 = (const float*)d_in[4];
    const float* wih0   = (const float*)d_in[5];
    const float* whh0   = (const float*)d_in[6];
    const float* bih0   = (const float*)d_in[7];
    const float* bhh0   = (const float*)d_in[8];
    const float* W_msg1 = (const float*)d_in[9];
    const float* wih1   = (const float*)d_in[10];
    const float* whh1   = (const float*)d_in[11];
    const float* bih1   = (const float*)d_in[12];
    const float* bhh1   = (const float*)d_in[13];
    const float* W_out  = (const float*)d_in[14];
    const float* b_out  = (const float*)d_in[15];
    float* out = (float*)d_out;

    const int* src = eidx;
    const int* dst = eidx + NE;

    char* ws = (char*)d_ws;
    size_t off = 0;
    auto alloc = [&](size_t bytes) {
        void* p = ws + off;
        off += (bytes + 255) & ~(size_t)255;
        return p;
    };
    short* bufA = (short*)alloc((size_t)NN * HD * 2);
    short* bufB = (short*)alloc((size_t)NN * HD * 2);
    short* bufC = (short*)alloc((size_t)NN * HD * 2);
    short* pWin  = (short*)alloc(8  * 4 * 64 * 8 * 2);
    short* pWm0  = (short*)alloc(8  * 4 * 64 * 8 * 2);
    short* pWm1  = (short*)alloc(8  * 4 * 64 * 8 * 2);
    short* pWout = (short*)alloc(2  * 4 * 64 * 8 * 2);
    short* pI0   = (short*)alloc(24 * 4 * 64 * 8 * 2);
    short* pH0   = (short*)alloc(24 * 4 * 64 * 8 * 2);
    short* pI1   = (short*)alloc(24 * 4 * 64 * 8 * 2);
    short* pH1   = (short*)alloc(24 * 4 * 64 * 8 * 2);
    int* counts  = (int*)alloc(NN * 4);
    int* offsets = (int*)alloc((NN + 1) * 4);
    int* cursor  = (int*)alloc(NN * 4);
    int* perm    = (int*)alloc(NE * 4);

    // CSR build
    hipMemsetAsync(counts, 0, NN * 4, stream);
    hist_kernel<<<(NE + 255) / 256, 256, 0, stream>>>(dst, counts);
    scan_kernel<<<1, 1024, 0, stream>>>(counts, offsets, cursor);
    fill_kernel<<<(NE + 255) / 256, 256, 0, stream>>>(src, dst, cursor, perm);

    // weight packing
    pack_all<<<dim3(24, 8), 256, 0, stream>>>(W_in, W_msg0, W_msg1, W_out,
                                              wih0, whh0, wih1, whh1,
                                              pWin, pWm0, pWm1, pWout, pI0, pH0, pI1, pH1);

    int g = (NN + 127) / 128;   // 391

    // h0 = relu(x @ W_in + b_in)   (fp32 A, bf16 out)
    gemm_mfma<8, true, true, false><<<g, 256, 0, stream>>>(x, pWin, b_in, bufA);

    // layer 0
    gemm_mfma<8, false, false, false><<<g, 256, 0, stream>>>(bufA, pWm0, nullptr, bufB);
    aggregate_bf16<<<(NN + 7) / 8, 256, 0, stream>>>(bufB, offsets, perm, bufC);
    gru_mfma<<<g, 256, 0, stream>>>(bufC, bufA, pI0, pH0, bih0, bhh0, bufB);

    // layer 1
    gemm_mfma<8, false, false, false><<<g, 256, 0, stream>>>(bufB, pWm1, nullptr, bufA);
    aggregate_bf16<<<(NN + 7) / 8, 256, 0, stream>>>(bufA, offsets, perm, bufC);
    gru_mfma<<<g, 256, 0, stream>>>(bufC, bufB, pI1, pH1, bih1, bhh1, bufA);

    // out = h @ W_out + b_out  (fp32 out)
    gemm_mfma<2, false, false, true><<<g, 256, 0, stream>>>(bufA, pWout, b_out, out);
}

// Round 6
// 402.196 us; speedup vs baseline: 2.3926x; 1.2563x over previous
//
#include <hip/hip_runtime.h>
#include <hip/hip_bf16.h>
#include <math.h>

#define NN 50000
#define NE 800000
#define HD 128
#define SCAN_BLOCKS 196   // 196 * 256 = 50176 >= NN

typedef __attribute__((ext_vector_type(8))) short bf16x8;
typedef __attribute__((ext_vector_type(4))) float f32x4;

__device__ inline float b2f(unsigned short s) {
    union { unsigned int u; float f; } w; w.u = ((unsigned int)s) << 16; return w.f;
}
__device__ inline short f2b(float f) {
    __hip_bfloat16 h = __float2bfloat16(f);
    short s; __builtin_memcpy(&s, &h, 2); return s;
}

// ---------------- CSR build ----------------
__global__ void hist_kernel(const int* __restrict__ dst, int* __restrict__ counts) {
    int e = blockIdx.x * blockDim.x + threadIdx.x;
    if (e < NE) atomicAdd(&counts[dst[e]], 1);
}

// stage 1: per-block sum of 256 counts
__global__ __launch_bounds__(256) void scan_partial_kernel(const int* __restrict__ counts,
                                                           int* __restrict__ partial) {
    __shared__ int sm[256];
    int i = blockIdx.x * 256 + threadIdx.x;
    sm[threadIdx.x] = (i < NN) ? counts[i] : 0;
    __syncthreads();
    for (int off = 128; off > 0; off >>= 1) {
        if (threadIdx.x < off) sm[threadIdx.x] += sm[threadIdx.x + off];
        __syncthreads();
    }
    if (threadIdx.x == 0) partial[blockIdx.x] = sm[0];
}

// stage 2: exclusive scan of the SCAN_BLOCKS partials (single small block)
__global__ __launch_bounds__(256) void scan_base_kernel(const int* __restrict__ partial,
                                                        int* __restrict__ base) {
    __shared__ int sm[256];
    int tid = threadIdx.x;
    int v = (tid < SCAN_BLOCKS) ? partial[tid] : 0;
    sm[tid] = v;
    __syncthreads();
    for (int off = 1; off < 256; off <<= 1) {
        int t = (tid >= off) ? sm[tid - off] : 0;
        __syncthreads();
        sm[tid] += t;
        __syncthreads();
    }
    if (tid < SCAN_BLOCKS) base[tid] = sm[tid] - v;   // exclusive
}

// stage 3: block-local exclusive scan + base -> offsets & cursor
__global__ __launch_bounds__(256) void scan_final_kernel(const int* __restrict__ counts,
                                                         const int* __restrict__ base,
                                                         int* __restrict__ offsets,
                                                         int* __restrict__ cursor) {
    __shared__ int sm[256];
    int tid = threadIdx.x;
    int i = blockIdx.x * 256 + tid;
    int v = (i < NN) ? counts[i] : 0;
    sm[tid] = v;
    __syncthreads();
    for (int off = 1; off < 256; off <<= 1) {
        int t = (tid >= off) ? sm[tid - off] : 0;
        __syncthreads();
        sm[tid] += t;
        __syncthreads();
    }
    if (i < NN) {
        int o = base[blockIdx.x] + sm[tid] - v;   // exclusive prefix
        offsets[i] = o;
        cursor[i]  = o;
        if (i == NN - 1) offsets[NN] = o + v;
    }
}

__global__ void fill_kernel(const int* __restrict__ src, const int* __restrict__ dst,
                            int* __restrict__ cursor, int* __restrict__ perm_src) {
    int e = blockIdx.x * blockDim.x + threadIdx.x;
    if (e < NE) {
        int d = dst[e];
        int pos = atomicAdd(&cursor[d], 1);
        perm_src[pos] = src[e];
    }
}

// ---------------- weight pack: into per-lane MFMA B-fragment layout ----------------
// Bp[jt][ks][l][i] = B[k][j],  j = jt*16 + (l&15),  k = ks*32 + (l>>4)*8 + i
__global__ void pack_all(const float* W_in, const float* W_msg0, const float* W_msg1,
                         const float* W_out, const float* wih0, const float* whh0,
                         const float* wih1, const float* whh1,
                         short* pWin, short* pWm0, short* pWm1, short* pWout,
                         short* pI0, short* pH0, short* pI1, short* pH1) {
    const float* src; short* dst; int JT; bool kmajor; int J;
    switch (blockIdx.y) {
        case 0: src = W_in;   dst = pWin;  JT = 8;  kmajor = true;  J = 128; break;
        case 1: src = W_msg0; dst = pWm0;  JT = 8;  kmajor = true;  J = 128; break;
        case 2: src = W_msg1; dst = pWm1;  JT = 8;  kmajor = true;  J = 128; break;
        case 3: src = W_out;  dst = pWout; JT = 2;  kmajor = true;  J = 32;  break;
        case 4: src = wih0;   dst = pI0;   JT = 24; kmajor = false; J = 384; break;
        case 5: src = whh0;   dst = pH0;   JT = 24; kmajor = false; J = 384; break;
        case 6: src = wih1;   dst = pI1;   JT = 24; kmajor = false; J = 384; break;
        default: src = whh1;  dst = pH1;   JT = 24; kmajor = false; J = 384; break;
    }
    int t = blockIdx.x * 256 + threadIdx.x;
    if (t >= JT * 4 * 64) return;
    int l = t & 63, ks = (t >> 6) & 3, jt = t >> 8;
    int j = jt * 16 + (l & 15);
    int k0 = ks * 32 + (l >> 4) * 8;
    bf16x8 tv;
    if (kmajor) {
        #pragma unroll
        for (int i = 0; i < 8; ++i) tv[i] = f2b(src[(k0 + i) * J + j]);
    } else {
        #pragma unroll
        for (int i = 0; i < 8; ++i) tv[i] = f2b(src[j * 128 + k0 + i]);
    }
    *reinterpret_cast<bf16x8*>(dst + t * 8) = tv;
}

// ---------------- skinny MFMA GEMM: C[M,16*JT] = act(A[M,128] @ B + bias) ----------------
template<int JT, bool RELU, bool AF32, bool OUTF32>
__global__ __launch_bounds__(256) void gemm_mfma(const void* __restrict__ Av,
                                                 const short* __restrict__ Bp,
                                                 const float* __restrict__ bias,
                                                 void* __restrict__ Cv) {
    int w = threadIdx.x >> 6;
    int l = threadIdx.x & 63;
    int r0 = blockIdx.x * 128 + w * 32;
    int lr = l & 15;
    int lk = (l >> 4) * 8;

    bf16x8 a[2][4];
    #pragma unroll
    for (int mt = 0; mt < 2; ++mt) {
        int row = r0 + mt * 16 + lr;
        if (row > NN - 1) row = NN - 1;
        #pragma unroll
        for (int ks = 0; ks < 4; ++ks) {
            if (AF32) {
                const float* ap = (const float*)Av + (size_t)row * HD + ks * 32 + lk;
                float4 v0 = *(const float4*)ap;
                float4 v1 = *(const float4*)(ap + 4);
                bf16x8 tv;
                tv[0] = f2b(v0.x); tv[1] = f2b(v0.y); tv[2] = f2b(v0.z); tv[3] = f2b(v0.w);
                tv[4] = f2b(v1.x); tv[5] = f2b(v1.y); tv[6] = f2b(v1.z); tv[7] = f2b(v1.w);
                a[mt][ks] = tv;
            } else {
                a[mt][ks] = *reinterpret_cast<const bf16x8*>((const short*)Av + (size_t)row * HD + ks * 32 + lk);
            }
        }
    }

    #pragma unroll
    for (int jt = 0; jt < JT; ++jt) {
        f32x4 acc0 = {0.f, 0.f, 0.f, 0.f}, acc1 = {0.f, 0.f, 0.f, 0.f};
        const short* bp = Bp + ((jt * 4) * 64 + l) * 8;
        #pragma unroll
        for (int ks = 0; ks < 4; ++ks) {
            bf16x8 b = *reinterpret_cast<const bf16x8*>(bp + ks * 64 * 8);
            acc0 = __builtin_amdgcn_mfma_f32_16x16x32_bf16(a[0][ks], b, acc0, 0, 0, 0);
            acc1 = __builtin_amdgcn_mfma_f32_16x16x32_bf16(a[1][ks], b, acc1, 0, 0, 0);
        }
        int col = jt * 16 + lr;
        float bs = bias ? bias[col] : 0.f;
        #pragma unroll
        for (int mt = 0; mt < 2; ++mt) {
            f32x4 acc = mt ? acc1 : acc0;
            #pragma unroll
            for (int rg = 0; rg < 4; ++rg) {
                int row = r0 + mt * 16 + (l >> 4) * 4 + rg;
                if (row < NN) {
                    float v = acc[rg] + bs;
                    if (RELU) v = fmaxf(v, 0.f);
                    if (OUTF32) ((float*)Cv)[(size_t)row * (16 * JT) + col] = v;
                    else        ((short*)Cv)[(size_t)row * (16 * JT) + col] = f2b(v);
                }
            }
        }
    }
}

// ---------------- CSR aggregate (bf16 in, fp32 accum, bf16 out) ----------------
__global__ __launch_bounds__(256) void aggregate_bf16(const short* __restrict__ m,
                                                      const int* __restrict__ offsets,
                                                      const int* __restrict__ perm_src,
                                                      short* __restrict__ agg) {
    int node = blockIdx.x * 8 + (threadIdx.x >> 5);
    if (node >= NN) return;
    int q = (threadIdx.x & 31) * 4;
    int beg = offsets[node], end = offsets[node + 1];
    float a0 = 0.f, a1 = 0.f, a2 = 0.f, a3 = 0.f;
    int e = beg;
    for (; e + 2 <= end; e += 2) {
        int s0 = perm_src[e], s1 = perm_src[e + 1];
        ushort4 u0 = *reinterpret_cast<const ushort4*>(m + (size_t)s0 * HD + q);
        ushort4 u1 = *reinterpret_cast<const ushort4*>(m + (size_t)s1 * HD + q);
        a0 += b2f(u0.x) + b2f(u1.x);
        a1 += b2f(u0.y) + b2f(u1.y);
        a2 += b2f(u0.z) + b2f(u1.z);
        a3 += b2f(u0.w) + b2f(u1.w);
    }
    if (e < end) {
        ushort4 u = *reinterpret_cast<const ushort4*>(m + (size_t)perm_src[e] * HD + q);
        a0 += b2f(u.x); a1 += b2f(u.y); a2 += b2f(u.z); a3 += b2f(u.w);
    }
    ushort4 o;
    o.x = (unsigned short)f2b(a0); o.y = (unsigned short)f2b(a1);
    o.z = (unsigned short)f2b(a2); o.w = (unsigned short)f2b(a3);
    *reinterpret_cast<ushort4*>(agg + (size_t)node * HD + q) = o;
}

// ---------------- fused GRU via MFMA ----------------
__global__ __launch_bounds__(256) void gru_mfma(const short* __restrict__ agg,
                                                const short* __restrict__ h,
                                                const short* __restrict__ BpI,
                                                const short* __restrict__ BpH,
                                                const float* __restrict__ bih,
                                                const float* __restrict__ bhh,
                                                short* __restrict__ hout) {
    int w = threadIdx.x >> 6;
    int l = threadIdx.x & 63;
    int r0 = blockIdx.x * 128 + w * 32;
    int lr = l & 15;
    int lk = (l >> 4) * 8;

    bf16x8 aa[2][4], ah[2][4];
    #pragma unroll
    for (int mt = 0; mt < 2; ++mt) {
        int row = r0 + mt * 16 + lr;
        if (row > NN - 1) row = NN - 1;
        #pragma unroll
        for (int ks = 0; ks < 4; ++ks) {
            aa[mt][ks] = *reinterpret_cast<const bf16x8*>(agg + (size_t)row * HD + ks * 32 + lk);
            ah[mt][ks] = *reinterpret_cast<const bf16x8*>(h   + (size_t)row * HD + ks * 32 + lk);
        }
    }

    const f32x4 zero = {0.f, 0.f, 0.f, 0.f};
    #pragma unroll 1
    for (int jt = 0; jt < 8; ++jt) {
        f32x4 ir[2] = {zero, zero}, iz[2] = {zero, zero}, in_[2] = {zero, zero};
        f32x4 hr[2] = {zero, zero}, hz[2] = {zero, zero}, hn[2] = {zero, zero};
        #pragma unroll
        for (int ks = 0; ks < 4; ++ks) {
            const short* bi = BpI + ((jt * 4 + ks) * 64 + l) * 8;
            const short* bh = BpH + ((jt * 4 + ks) * 64 + l) * 8;
            bf16x8 bir = *reinterpret_cast<const bf16x8*>(bi);
            bf16x8 biz = *reinterpret_cast<const bf16x8*>(bi + 8 * 4 * 64 * 8);
            bf16x8 bin = *reinterpret_cast<const bf16x8*>(bi + 16 * 4 * 64 * 8);
            bf16x8 bhr = *reinterpret_cast<const bf16x8*>(bh);
            bf16x8 bhz = *reinterpret_cast<const bf16x8*>(bh + 8 * 4 * 64 * 8);
            bf16x8 bhn = *reinterpret_cast<const bf16x8*>(bh + 16 * 4 * 64 * 8);
            #pragma unroll
            for (int mt = 0; mt < 2; ++mt) {
                ir[mt]  = __builtin_amdgcn_mfma_f32_16x16x32_bf16(aa[mt][ks], bir, ir[mt],  0, 0, 0);
                iz[mt]  = __builtin_amdgcn_mfma_f32_16x16x32_bf16(aa[mt][ks], biz, iz[mt],  0, 0, 0);
                in_[mt] = __builtin_amdgcn_mfma_f32_16x16x32_bf16(aa[mt][ks], bin, in_[mt], 0, 0, 0);
                hr[mt]  = __builtin_amdgcn_mfma_f32_16x16x32_bf16(ah[mt][ks], bhr, hr[mt],  0, 0, 0);
                hz[mt]  = __builtin_amdgcn_mfma_f32_16x16x32_bf16(ah[mt][ks], bhz, hz[mt],  0, 0, 0);
                hn[mt]  = __builtin_amdgcn_mfma_f32_16x16x32_bf16(ah[mt][ks], bhn, hn[mt],  0, 0, 0);
            }
        }
        int col = jt * 16 + lr;
        float bir_ = bih[col], biz_ = bih[128 + col], bin_ = bih[256 + col];
        float bhr_ = bhh[col], bhz_ = bhh[128 + col], bhn_ = bhh[256 + col];
        #pragma unroll
        for (int mt = 0; mt < 2; ++mt) {
            #pragma unroll
            for (int rg = 0; rg < 4; ++rg) {
                int row = r0 + mt * 16 + (l >> 4) * 4 + rg;
                if (row < NN) {
                    float rr = 1.f / (1.f + __expf(-(ir[mt][rg] + bir_ + hr[mt][rg] + bhr_)));
                    float zz = 1.f / (1.f + __expf(-(iz[mt][rg] + biz_ + hz[mt][rg] + bhz_)));
                    float pre = in_[mt][rg] + bin_ + rr * (hn[mt][rg] + bhn_);
                    pre = fminf(fmaxf(pre, -20.f), 20.f);
                    float e2 = __expf(2.f * pre);
                    float nn_ = (e2 - 1.f) / (e2 + 1.f);
                    float hv = b2f((unsigned short)h[(size_t)row * HD + col]);
                    hout[(size_t)row * HD + col] = f2b((1.f - zz) * nn_ + zz * hv);
                }
            }
        }
    }
}

// ---------------- launch ----------------
extern "C" void kernel_launch(void* const* d_in, const int* in_sizes, int n_in,
                              void* d_out, int out_size, void* d_ws, size_t ws_size,
                              hipStream_t stream) {
    const float* x      = (const float*)d_in[0];
    const int*   eidx   = (const int*)d_in[1];
    const float* W_in   = (const float*)d_in[2];
    const float* b_in   = (const float*)d_in[3];
    const float* W_msg0 = (const float*)d_in[4];
    const float* wih0   = (const float*)d_in[5];
    const float* whh0   = (const float*)d_in[6];
    const float* bih0   = (const float*)d_in[7];
    const float* bhh0   = (const float*)d_in[8];
    const float* W_msg1 = (const float*)d_in[9];
    const float* wih1   = (const float*)d_in[10];
    const float* whh1   = (const float*)d_in[11];
    const float* bih1   = (const float*)d_in[12];
    const float* bhh1   = (const float*)d_in[13];
    const float* W_out  = (const float*)d_in[14];
    const float* b_out  = (const float*)d_in[15];
    float* out = (float*)d_out;

    const int* src = eidx;
    const int* dst = eidx + NE;

    char* ws = (char*)d_ws;
    size_t off = 0;
    auto alloc = [&](size_t bytes) {
        void* p = ws + off;
        off += (bytes + 255) & ~(size_t)255;
        return p;
    };
    short* bufA = (short*)alloc((size_t)NN * HD * 2);
    short* bufB = (short*)alloc((size_t)NN * HD * 2);
    short* bufC = (short*)alloc((size_t)NN * HD * 2);
    short* pWin  = (short*)alloc(8  * 4 * 64 * 8 * 2);
    short* pWm0  = (short*)alloc(8  * 4 * 64 * 8 * 2);
    short* pWm1  = (short*)alloc(8  * 4 * 64 * 8 * 2);
    short* pWout = (short*)alloc(2  * 4 * 64 * 8 * 2);
    short* pI0   = (short*)alloc(24 * 4 * 64 * 8 * 2);
    short* pH0   = (short*)alloc(24 * 4 * 64 * 8 * 2);
    short* pI1   = (short*)alloc(24 * 4 * 64 * 8 * 2);
    short* pH1   = (short*)alloc(24 * 4 * 64 * 8 * 2);
    int* counts  = (int*)alloc(NN * 4);
    int* offsets = (int*)alloc((NN + 1) * 4);
    int* cursor  = (int*)alloc(NN * 4);
    int* perm    = (int*)alloc(NE * 4);
    int* partial = (int*)alloc(SCAN_BLOCKS * 4);
    int* pbase   = (int*)alloc(SCAN_BLOCKS * 4);

    // CSR build (parallel scan)
    hipMemsetAsync(counts, 0, NN * 4, stream);
    hist_kernel<<<(NE + 255) / 256, 256, 0, stream>>>(dst, counts);
    scan_partial_kernel<<<SCAN_BLOCKS, 256, 0, stream>>>(counts, partial);
    scan_base_kernel<<<1, 256, 0, stream>>>(partial, pbase);
    scan_final_kernel<<<SCAN_BLOCKS, 256, 0, stream>>>(counts, pbase, offsets, cursor);
    fill_kernel<<<(NE + 255) / 256, 256, 0, stream>>>(src, dst, cursor, perm);

    // weight packing
    pack_all<<<dim3(24, 8), 256, 0, stream>>>(W_in, W_msg0, W_msg1, W_out,
                                              wih0, whh0, wih1, whh1,
                                              pWin, pWm0, pWm1, pWout, pI0, pH0, pI1, pH1);

    int g = (NN + 127) / 128;   // 391

    // h0 = relu(x @ W_in + b_in)   (fp32 A, bf16 out)
    gemm_mfma<8, true, true, false><<<g, 256, 0, stream>>>(x, pWin, b_in, bufA);

    // layer 0
    gemm_mfma<8, false, false, false><<<g, 256, 0, stream>>>(bufA, pWm0, nullptr, bufB);
    aggregate_bf16<<<(NN + 7) / 8, 256, 0, stream>>>(bufB, offsets, perm, bufC);
    gru_mfma<<<g, 256, 0, stream>>>(bufC, bufA, pI0, pH0, bih0, bhh0, bufB);

    // layer 1
    gemm_mfma<8, false, false, false><<<g, 256, 0, stream>>>(bufB, pWm1, nullptr, bufA);
    aggregate_bf16<<<(NN + 7) / 8, 256, 0, stream>>>(bufA, offsets, perm, bufC);
    gru_mfma<<<g, 256, 0, stream>>>(bufC, bufB, pI1, pH1, bih1, bhh1, bufA);

    // out = h @ W_out + b_out  (fp32 out)
    gemm_mfma<2, false, false, true><<<g, 256, 0, stream>>>(bufA, pWout, b_out, out);
}

// Round 8
// 389.129 us; speedup vs baseline: 2.4730x; 1.0336x over previous
//
#include <hip/hip_runtime.h>
#include <hip/hip_bf16.h>
#include <math.h>

#define NN 50000
#define NE 800000
#define HD 128
#define SCAN_BLOCKS 196   // 196 * 256 = 50176 >= NN
#define FILL_CHUNK 4096   // edges per fill block
#define FILL_CHUNKS ((NE + FILL_CHUNK - 1) / FILL_CHUNK)   // 196
#define NPART 8           // dst partitions, pinned to XCDs via blockIdx&7

typedef __attribute__((ext_vector_type(8))) short bf16x8;
typedef __attribute__((ext_vector_type(4))) float f32x4;

__device__ inline float b2f(unsigned short s) {
    union { unsigned int u; float f; } w; w.u = ((unsigned int)s) << 16; return w.f;
}
__device__ inline short f2b(float f) {
    __hip_bfloat16 h = __float2bfloat16(f);
    short s; __builtin_memcpy(&s, &h, 2); return s;
}

// ---------------- CSR build ----------------
__global__ void hist_kernel(const int* __restrict__ dst, int* __restrict__ counts) {
    int e = blockIdx.x * blockDim.x + threadIdx.x;
    if (e < NE) atomicAdd(&counts[dst[e]], 1);
}

// stage 1: per-block sum of 256 counts
__global__ __launch_bounds__(256) void scan_partial_kernel(const int* __restrict__ counts,
                                                           int* __restrict__ partial) {
    __shared__ int sm[256];
    int i = blockIdx.x * 256 + threadIdx.x;
    sm[threadIdx.x] = (i < NN) ? counts[i] : 0;
    __syncthreads();
    for (int off = 128; off > 0; off >>= 1) {
        if (threadIdx.x < off) sm[threadIdx.x] += sm[threadIdx.x + off];
        __syncthreads();
    }
    if (threadIdx.x == 0) partial[blockIdx.x] = sm[0];
}

// stage 2: exclusive scan of the SCAN_BLOCKS partials (single small block)
__global__ __launch_bounds__(256) void scan_base_kernel(const int* __restrict__ partial,
                                                        int* __restrict__ base) {
    __shared__ int sm[256];
    int tid = threadIdx.x;
    int v = (tid < SCAN_BLOCKS) ? partial[tid] : 0;
    sm[tid] = v;
    __syncthreads();
    for (int off = 1; off < 256; off <<= 1) {
        int t = (tid >= off) ? sm[tid - off] : 0;
        __syncthreads();
        sm[tid] += t;
        __syncthreads();
    }
    if (tid < SCAN_BLOCKS) base[tid] = sm[tid] - v;   // exclusive
}

// stage 3: block-local exclusive scan + base -> offsets & cursor
__global__ __launch_bounds__(256) void scan_final_kernel(const int* __restrict__ counts,
                                                         const int* __restrict__ base,
                                                         int* __restrict__ offsets,
                                                         int* __restrict__ cursor) {
    __shared__ int sm[256];
    int tid = threadIdx.x;
    int i = blockIdx.x * 256 + tid;
    int v = (i < NN) ? counts[i] : 0;
    sm[tid] = v;
    __syncthreads();
    for (int off = 1; off < 256; off <<= 1) {
        int t = (tid >= off) ? sm[tid - off] : 0;
        __syncthreads();
        sm[tid] += t;
        __syncthreads();
    }
    if (i < NN) {
        int o = base[blockIdx.x] + sm[tid] - v;   // exclusive prefix
        offsets[i] = o;
        cursor[i]  = o;
        if (i == NN - 1) offsets[NN] = o + v;
    }
}

// XCD-partitioned fill: block b -> partition p=b&7 (XCD heuristic), chunk c=b>>3.
// Each perm cache line (contiguous per dst range) is written by one XCD's L2 only,
// killing the 16x partial-line write amplification of the naive scatter.
__global__ __launch_bounds__(256) void fill_part_kernel(const int* __restrict__ src,
                                                        const int* __restrict__ dst,
                                                        int* __restrict__ cursor,
                                                        int* __restrict__ perm_src) {
    int part  = blockIdx.x & (NPART - 1);
    int chunk = blockIdx.x >> 3;
    int lo = part * (NN / NPART);
    int hi = (part == NPART - 1) ? NN : lo + (NN / NPART);
    int e0 = chunk * FILL_CHUNK;
    int e1 = min(e0 + FILL_CHUNK, NE);
    for (int e = e0 + threadIdx.x; e < e1; e += 256) {
        int d = dst[e];
        if (d >= lo && d < hi) {
            int pos = atomicAdd(&cursor[d], 1);
            perm_src[pos] = src[e];
        }
    }
}

// ---------------- weight pack: into per-lane MFMA B-fragment layout ----------------
// Bp[jt][ks][l][i] = B[k][j],  j = jt*16 + (l&15),  k = ks*32 + (l>>4)*8 + i
__global__ void pack_all(const float* W_in, const float* W_msg0, const float* W_msg1,
                         const float* W_out, const float* wih0, const float* whh0,
                         const float* wih1, const float* whh1,
                         short* pWin, short* pWm0, short* pWm1, short* pWout,
                         short* pI0, short* pH0, short* pI1, short* pH1) {
    const float* src; short* dst; int JT; bool kmajor; int J;
    switch (blockIdx.y) {
        case 0: src = W_in;   dst = pWin;  JT = 8;  kmajor = true;  J = 128; break;
        case 1: src = W_msg0; dst = pWm0;  JT = 8;  kmajor = true;  J = 128; break;
        case 2: src = W_msg1; dst = pWm1;  JT = 8;  kmajor = true;  J = 128; break;
        case 3: src = W_out;  dst = pWout; JT = 2;  kmajor = true;  J = 32;  break;
        case 4: src = wih0;   dst = pI0;   JT = 24; kmajor = false; J = 384; break;
        case 5: src = whh0;   dst = pH0;   JT = 24; kmajor = false; J = 384; break;
        case 6: src = wih1;   dst = pI1;   JT = 24; kmajor = false; J = 384; break;
        default: src = whh1;  dst = pH1;   JT = 24; kmajor = false; J = 384; break;
    }
    int t = blockIdx.x * 256 + threadIdx.x;
    if (t >= JT * 4 * 64) return;
    int l = t & 63, ks = (t >> 6) & 3, jt = t >> 8;
    int j = jt * 16 + (l & 15);
    int k0 = ks * 32 + (l >> 4) * 8;
    bf16x8 tv;
    if (kmajor) {
        #pragma unroll
        for (int i = 0; i < 8; ++i) tv[i] = f2b(src[(k0 + i) * J + j]);
    } else {
        #pragma unroll
        for (int i = 0; i < 8; ++i) tv[i] = f2b(src[j * 128 + k0 + i]);
    }
    *reinterpret_cast<bf16x8*>(dst + t * 8) = tv;
}

// ---------------- skinny MFMA GEMM: C[M,16*JT] = act(A[M,128] @ B + bias) ----------------
template<int JT, bool RELU, bool AF32, bool OUTF32>
__global__ __launch_bounds__(256) void gemm_mfma(const void* __restrict__ Av,
                                                 const short* __restrict__ Bp,
                                                 const float* __restrict__ bias,
                                                 void* __restrict__ Cv) {
    int w = threadIdx.x >> 6;
    int l = threadIdx.x & 63;
    int r0 = blockIdx.x * 128 + w * 32;
    int lr = l & 15;
    int lk = (l >> 4) * 8;

    bf16x8 a[2][4];
    #pragma unroll
    for (int mt = 0; mt < 2; ++mt) {
        int row = r0 + mt * 16 + lr;
        if (row > NN - 1) row = NN - 1;
        #pragma unroll
        for (int ks = 0; ks < 4; ++ks) {
            if (AF32) {
                const float* ap = (const float*)Av + (size_t)row * HD + ks * 32 + lk;
                float4 v0 = *(const float4*)ap;
                float4 v1 = *(const float4*)(ap + 4);
                bf16x8 tv;
                tv[0] = f2b(v0.x); tv[1] = f2b(v0.y); tv[2] = f2b(v0.z); tv[3] = f2b(v0.w);
                tv[4] = f2b(v1.x); tv[5] = f2b(v1.y); tv[6] = f2b(v1.z); tv[7] = f2b(v1.w);
                a[mt][ks] = tv;
            } else {
                a[mt][ks] = *reinterpret_cast<const bf16x8*>((const short*)Av + (size_t)row * HD + ks * 32 + lk);
            }
        }
    }

    #pragma unroll
    for (int jt = 0; jt < JT; ++jt) {
        f32x4 acc0 = {0.f, 0.f, 0.f, 0.f}, acc1 = {0.f, 0.f, 0.f, 0.f};
        const short* bp = Bp + ((jt * 4) * 64 + l) * 8;
        #pragma unroll
        for (int ks = 0; ks < 4; ++ks) {
            bf16x8 b = *reinterpret_cast<const bf16x8*>(bp + ks * 64 * 8);
            acc0 = __builtin_amdgcn_mfma_f32_16x16x32_bf16(a[0][ks], b, acc0, 0, 0, 0);
            acc1 = __builtin_amdgcn_mfma_f32_16x16x32_bf16(a[1][ks], b, acc1, 0, 0, 0);
        }
        int col = jt * 16 + lr;
        float bs = bias ? bias[col] : 0.f;
        #pragma unroll
        for (int mt = 0; mt < 2; ++mt) {
            f32x4 acc = mt ? acc1 : acc0;
            #pragma unroll
            for (int rg = 0; rg < 4; ++rg) {
                int row = r0 + mt * 16 + (l >> 4) * 4 + rg;
                if (row < NN) {
                    float v = acc[rg] + bs;
                    if (RELU) v = fmaxf(v, 0.f);
                    if (OUTF32) ((float*)Cv)[(size_t)row * (16 * JT) + col] = v;
                    else        ((short*)Cv)[(size_t)row * (16 * JT) + col] = f2b(v);
                }
            }
        }
    }
}

// ---------------- CSR aggregate (bf16 in, fp32 accum, bf16 out) ----------------
__global__ __launch_bounds__(256) void aggregate_bf16(const short* __restrict__ m,
                                                      const int* __restrict__ offsets,
                                                      const int* __restrict__ perm_src,
                                                      short* __restrict__ agg) {
    int node = blockIdx.x * 8 + (threadIdx.x >> 5);
    if (node >= NN) return;
    int q = (threadIdx.x & 31) * 4;
    int beg = offsets[node], end = offsets[node + 1];
    float a0 = 0.f, a1 = 0.f, a2 = 0.f, a3 = 0.f;
    int e = beg;
    for (; e + 2 <= end; e += 2) {
        int s0 = perm_src[e], s1 = perm_src[e + 1];
        ushort4 u0 = *reinterpret_cast<const ushort4*>(m + (size_t)s0 * HD + q);
        ushort4 u1 = *reinterpret_cast<const ushort4*>(m + (size_t)s1 * HD + q);
        a0 += b2f(u0.x) + b2f(u1.x);
        a1 += b2f(u0.y) + b2f(u1.y);
        a2 += b2f(u0.z) + b2f(u1.z);
        a3 += b2f(u0.w) + b2f(u1.w);
    }
    if (e < end) {
        ushort4 u = *reinterpret_cast<const ushort4*>(m + (size_t)perm_src[e] * HD + q);
        a0 += b2f(u.x); a1 += b2f(u.y); a2 += b2f(u.z); a3 += b2f(u.w);
    }
    ushort4 o;
    o.x = (unsigned short)f2b(a0); o.y = (unsigned short)f2b(a1);
    o.z = (unsigned short)f2b(a2); o.w = (unsigned short)f2b(a3);
    *reinterpret_cast<ushort4*>(agg + (size_t)node * HD + q) = o;
}

// ---------------- fused GRU via MFMA ----------------
__global__ __launch_bounds__(256) void gru_mfma(const short* __restrict__ agg,
                                                const short* __restrict__ h,
                                                const short* __restrict__ BpI,
                                                const short* __restrict__ BpH,
                                                const float* __restrict__ bih,
                                                const float* __restrict__ bhh,
                                                short* __restrict__ hout) {
    int w = threadIdx.x >> 6;
    int l = threadIdx.x & 63;
    int r0 = blockIdx.x * 128 + w * 32;
    int lr = l & 15;
    int lk = (l >> 4) * 8;

    bf16x8 aa[2][4], ah[2][4];
    #pragma unroll
    for (int mt = 0; mt < 2; ++mt) {
        int row = r0 + mt * 16 + lr;
        if (row > NN - 1) row = NN - 1;
        #pragma unroll
        for (int ks = 0; ks < 4; ++ks) {
            aa[mt][ks] = *reinterpret_cast<const bf16x8*>(agg + (size_t)row * HD + ks * 32 + lk);
            ah[mt][ks] = *reinterpret_cast<const bf16x8*>(h   + (size_t)row * HD + ks * 32 + lk);
        }
    }

    const f32x4 zero = {0.f, 0.f, 0.f, 0.f};
    #pragma unroll 1
    for (int jt = 0; jt < 8; ++jt) {
        f32x4 ir[2] = {zero, zero}, iz[2] = {zero, zero}, in_[2] = {zero, zero};
        f32x4 hr[2] = {zero, zero}, hz[2] = {zero, zero}, hn[2] = {zero, zero};
        #pragma unroll
        for (int ks = 0; ks < 4; ++ks) {
            const short* bi = BpI + ((jt * 4 + ks) * 64 + l) * 8;
            const short* bh = BpH + ((jt * 4 + ks) * 64 + l) * 8;
            bf16x8 bir = *reinterpret_cast<const bf16x8*>(bi);
            bf16x8 biz = *reinterpret_cast<const bf16x8*>(bi + 8 * 4 * 64 * 8);
            bf16x8 bin = *reinterpret_cast<const bf16x8*>(bi + 16 * 4 * 64 * 8);
            bf16x8 bhr = *reinterpret_cast<const bf16x8*>(bh);
            bf16x8 bhz = *reinterpret_cast<const bf16x8*>(bh + 8 * 4 * 64 * 8);
            bf16x8 bhn = *reinterpret_cast<const bf16x8*>(bh + 16 * 4 * 64 * 8);
            #pragma unroll
            for (int mt = 0; mt < 2; ++mt) {
                ir[mt]  = __builtin_amdgcn_mfma_f32_16x16x32_bf16(aa[mt][ks], bir, ir[mt],  0, 0, 0);
                iz[mt]  = __builtin_amdgcn_mfma_f32_16x16x32_bf16(aa[mt][ks], biz, iz[mt],  0, 0, 0);
                in_[mt] = __builtin_amdgcn_mfma_f32_16x16x32_bf16(aa[mt][ks], bin, in_[mt], 0, 0, 0);
                hr[mt]  = __builtin_amdgcn_mfma_f32_16x16x32_bf16(ah[mt][ks], bhr, hr[mt],  0, 0, 0);
                hz[mt]  = __builtin_amdgcn_mfma_f32_16x16x32_bf16(ah[mt][ks], bhz, hz[mt],  0, 0, 0);
                hn[mt]  = __builtin_amdgcn_mfma_f32_16x16x32_bf16(ah[mt][ks], bhn, hn[mt],  0, 0, 0);
            }
        }
        int col = jt * 16 + lr;
        float bir_ = bih[col], biz_ = bih[128 + col], bin_ = bih[256 + col];
        float bhr_ = bhh[col], bhz_ = bhh[128 + col], bhn_ = bhh[256 + col];
        #pragma unroll
        for (int mt = 0; mt < 2; ++mt) {
            #pragma unroll
            for (int rg = 0; rg < 4; ++rg) {
                int row = r0 + mt * 16 + (l >> 4) * 4 + rg;
                if (row < NN) {
                    float rr = 1.f / (1.f + __expf(-(ir[mt][rg] + bir_ + hr[mt][rg] + bhr_)));
                    float zz = 1.f / (1.f + __expf(-(iz[mt][rg] + biz_ + hz[mt][rg] + bhz_)));
                    float pre = in_[mt][rg] + bin_ + rr * (hn[mt][rg] + bhn_);
                    pre = fminf(fmaxf(pre, -20.f), 20.f);
                    float e2 = __expf(2.f * pre);
                    float nn_ = (e2 - 1.f) / (e2 + 1.f);
                    float hv = b2f((unsigned short)h[(size_t)row * HD + col]);
                    hout[(size_t)row * HD + col] = f2b((1.f - zz) * nn_ + zz * hv);
                }
            }
        }
    }
}

// ---------------- launch ----------------
extern "C" void kernel_launch(void* const* d_in, const int* in_sizes, int n_in,
                              void* d_out, int out_size, void* d_ws, size_t ws_size,
                              hipStream_t stream) {
    const float* x      = (const float*)d_in[0];
    const int*   eidx   = (const int*)d_in[1];
    const float* W_in   = (const float*)d_in[2];
    const float* b_in   = (const float*)d_in[3];
    const float* W_msg0 = (const float*)d_in[4];
    const float* wih0   = (const float*)d_in[5];
    const float* whh0   = (const float*)d_in[6];
    const float* bih0   = (const float*)d_in[7];
    const float* bhh0   = (const float*)d_in[8];
    const float* W_msg1 = (const float*)d_in[9];
    const float* wih1   = (const float*)d_in[10];
    const float* whh1   = (const float*)d_in[11];
    const float* bih1   = (const float*)d_in[12];
    const float* bhh1   = (const float*)d_in[13];
    const float* W_out  = (const float*)d_in[14];
    const float* b_out  = (const float*)d_in[15];
    float* out = (float*)d_out;

    const int* src = eidx;
    const int* dst = eidx + NE;

    char* ws = (char*)d_ws;
    size_t off = 0;
    auto alloc = [&](size_t bytes) {
        void* p = ws + off;
        off += (bytes + 255) & ~(size_t)255;
        return p;
    };
    short* bufA = (short*)alloc((size_t)NN * HD * 2);
    short* bufB = (short*)alloc((size_t)NN * HD * 2);
    short* bufC = (short*)alloc((size_t)NN * HD * 2);
    short* pWin  = (short*)alloc(8  * 4 * 64 * 8 * 2);
    short* pWm0  = (short*)alloc(8  * 4 * 64 * 8 * 2);
    short* pWm1  = (short*)alloc(8  * 4 * 64 * 8 * 2);
    short* pWout = (short*)alloc(2  * 4 * 64 * 8 * 2);
    short* pI0   = (short*)alloc(24 * 4 * 64 * 8 * 2);
    short* pH0   = (short*)alloc(24 * 4 * 64 * 8 * 2);
    short* pI1   = (short*)alloc(24 * 4 * 64 * 8 * 2);
    short* pH1   = (short*)alloc(24 * 4 * 64 * 8 * 2);
    int* counts  = (int*)alloc(NN * 4);
    int* offsets = (int*)alloc((NN + 1) * 4);
    int* cursor  = (int*)alloc(NN * 4);
    int* perm    = (int*)alloc(NE * 4);
    int* partial = (int*)alloc(SCAN_BLOCKS * 4);
    int* pbase   = (int*)alloc(SCAN_BLOCKS * 4);

    // CSR build (parallel scan + XCD-partitioned fill)
    hipMemsetAsync(counts, 0, NN * 4, stream);
    hist_kernel<<<(NE + 255) / 256, 256, 0, stream>>>(dst, counts);
    scan_partial_kernel<<<SCAN_BLOCKS, 256, 0, stream>>>(counts, partial);
    scan_base_kernel<<<1, 256, 0, stream>>>(partial, pbase);
    scan_final_kernel<<<SCAN_BLOCKS, 256, 0, stream>>>(counts, pbase, offsets, cursor);
    fill_part_kernel<<<NPART * FILL_CHUNKS, 256, 0, stream>>>(src, dst, cursor, perm);

    // weight packing
    pack_all<<<dim3(24, 8), 256, 0, stream>>>(W_in, W_msg0, W_msg1, W_out,
                                              wih0, whh0, wih1, whh1,
                                              pWin, pWm0, pWm1, pWout, pI0, pH0, pI1, pH1);

    int g = (NN + 127) / 128;   // 391

    // h0 = relu(x @ W_in + b_in)   (fp32 A, bf16 out)
    gemm_mfma<8, true, true, false><<<g, 256, 0, stream>>>(x, pWin, b_in, bufA);

    // layer 0
    gemm_mfma<8, false, false, false><<<g, 256, 0, stream>>>(bufA, pWm0, nullptr, bufB);
    aggregate_bf16<<<(NN + 7) / 8, 256, 0, stream>>>(bufB, offsets, perm, bufC);
    gru_mfma<<<g, 256, 0, stream>>>(bufC, bufA, pI0, pH0, bih0, bhh0, bufB);

    // layer 1
    gemm_mfma<8, false, false, false><<<g, 256, 0, stream>>>(bufB, pWm1, nullptr, bufA);
    aggregate_bf16<<<(NN + 7) / 8, 256, 0, stream>>>(bufA, offsets, perm, bufC);
    gru_mfma<<<g, 256, 0, stream>>>(bufC, bufB, pI1, pH1, bih1, bhh1, bufA);

    // out = h @ W_out + b_out  (fp32 out)
    gemm_mfma<2, false, false, true><<<g, 256, 0, stream>>>(bufA, pWout, b_out, out);
}